// Round 9
// baseline (175.617 us; speedup 1.0000x reference)
//
#include <hip/hip_runtime.h>
#include <hip/hip_bf16.h>

#define B_ 4
#define S_ 2048
#define D_ 512
#define H_ 8
#define A_ 64

typedef __attribute__((ext_vector_type(8))) __bf16 bf16x8;
typedef __attribute__((ext_vector_type(4))) __bf16 bf16x4;
typedef __attribute__((ext_vector_type(4))) float f32x4;

static __device__ __forceinline__ f32x4 mfma16(bf16x8 a, bf16x8 b, f32x4 c) {
  return __builtin_amdgcn_mfma_f32_16x16x32_bf16(a, b, c, 0, 0, 0);
}

static __device__ __forceinline__ f32x4 zero4() {
  f32x4 z = {0.f, 0.f, 0.f, 0.f};
  return z;
}

// 0.125 (1/sqrt(A)) * log2(e): scores are consumed by v_exp (2^x) in flash_kernel
#define QSCALE 0.18033688011f

#if __has_builtin(__builtin_amdgcn_exp2f)
#define EXP2(x) __builtin_amdgcn_exp2f(x)
#else
#define EXP2(x) exp2f(x)
#endif

// async global->LDS, 16B per lane, lds dest = wave-uniform base + lane*16
#define GLDS(g, l)                                                      \
  __builtin_amdgcn_global_load_lds(                                     \
      (const __attribute__((address_space(1))) void*)(g),               \
      (__attribute__((address_space(3))) void*)(l), 16, 0, 0)

// ------------- merged input prep: fp32->bf16 activations + LDS-transposed weights -------------
__global__ void prep_all_kernel(const float* __restrict__ q, const float* __restrict__ k,
                                const float* __restrict__ v,
                                const float* __restrict__ Wq, const float* __restrict__ Wk,
                                const float* __restrict__ Wv, const float* __restrict__ Wo,
                                __bf16* __restrict__ xq, __bf16* __restrict__ xk,
                                __bf16* __restrict__ xv,
                                __bf16* __restrict__ tq, __bf16* __restrict__ tk,
                                __bf16* __restrict__ tv, __bf16* __restrict__ to_) {
  __shared__ float tile[64][65];
  if (blockIdx.x < 12288) {
    int idx = blockIdx.x * 256 + threadIdx.x;  // 3 * 2^20 threads, one float4 each
    int which = idx >> 20;
    int i = idx & ((1 << 20) - 1);
    const float4* s = (const float4*)(which == 0 ? q : (which == 1 ? k : v));
    __bf16* d = (which == 0) ? xq : (which == 1 ? xk : xv);
    float4 f = s[i];
    bf16x4 o;
    o.x = (__bf16)f.x; o.y = (__bf16)f.y; o.z = (__bf16)f.z; o.w = (__bf16)f.w;
    *(bf16x4*)(d + 4 * i) = o;
  } else {
    int t = blockIdx.x - 12288;   // 0..255
    if (t < 192) {
      // Wq/Wk/Wv: tq[n=h*64+a][k=d] = W[h][d][a] (coalesced both sides via LDS transpose)
      int mat = t >> 6;
      int h = (t >> 3) & 7;
      int d0 = (t & 7) * 64;
      const float* W = (mat == 0) ? Wq : (mat == 1 ? Wk : Wv);
      __bf16* dst = (mat == 0) ? tq : (mat == 1 ? tk : tv);
      float sc = (mat == 0) ? QSCALE : 1.0f;   // fold 1/sqrt(A)*log2e into Q projection
      int a = threadIdx.x & 63, r0 = threadIdx.x >> 6;
#pragma unroll
      for (int i = 0; i < 16; i++) {
        int dd = r0 * 16 + i;
        tile[dd][a] = W[(h * D_ + d0 + dd) * A_ + a] * sc;
      }
      __syncthreads();
      int dd = threadIdx.x & 63, a0 = threadIdx.x >> 6;
#pragma unroll
      for (int i = 0; i < 16; i++) {
        int a2 = a0 * 16 + i;
        dst[(h * 64 + a2) * D_ + d0 + dd] = (__bf16)tile[dd][a2];
      }
    } else {
      // Wo: Wot[n=d][k=f] = Wo[f][d]
      int t2 = t - 192;           // 0..63
      int f0 = (t2 >> 3) * 64, d0 = (t2 & 7) * 64;
      int d = threadIdx.x & 63, r0 = threadIdx.x >> 6;
#pragma unroll
      for (int i = 0; i < 16; i++) {
        int ff = r0 * 16 + i;
        tile[ff][d] = Wo[(f0 + ff) * D_ + d0 + d];
      }
      __syncthreads();
      int f = threadIdx.x & 63, a0 = threadIdx.x >> 6;
#pragma unroll
      for (int i = 0; i < 16; i++) {
        int dd = a0 * 16 + i;
        to_[(d0 + dd) * D_ + f0 + f] = (__bf16)tile[f][dd];
      }
    }
  }
}

// ---------------- QKV projection GEMM: [8192x512] @ [512x512] per matrix ----------------
// 128x128 tile, 4 waves 2x2, BK=64, double-buffered global_load_lds staging (16B-granule XOR
// swizzle on both sides). Round-4 verified.
__global__ __launch_bounds__(256) void proj_gemm_kernel(
    const __bf16* __restrict__ Xq, const __bf16* __restrict__ Xk, const __bf16* __restrict__ Xv,
    const __bf16* __restrict__ Wtq, const __bf16* __restrict__ Wtk, const __bf16* __restrict__ Wtv,
    const float* __restrict__ bq, const float* __restrict__ bk, const float* __restrict__ bv,
    __bf16* __restrict__ Qb, __bf16* __restrict__ Kb, __bf16* __restrict__ Vtb) {
  int z = blockIdx.z;
  const __bf16* X  = (z == 0) ? Xq  : (z == 1 ? Xk  : Xv);
  const __bf16* Wt = (z == 0) ? Wtq : (z == 1 ? Wtk : Wtv);
  const float* bias = (z == 0) ? bq : (z == 1 ? bk : bv);
  float bscale = (z == 0) ? QSCALE : 1.0f;

  int lane = threadIdx.x & 63, wv = threadIdx.x >> 6;
  int wr = wv >> 1, wc = wv & 1;
  int quad = lane >> 4, lc = lane & 15;
  int M0 = blockIdx.x * 128, N0 = blockIdx.y * 128;
  int m0 = M0 + wr * 64, n0 = N0 + wc * 64;

  // 64 KiB: [buf][A|B][128][64]; epilogue staging aliases this after the loop
  __shared__ __align__(16) __bf16 smem[2 * 2 * 128 * 64];
#define AB(buf) (smem + (buf) * 16384)
#define BB(buf) (smem + (buf) * 16384 + 8192)

  int srow = lane >> 3;                 // 0..7
  int sg = ((lane & 7) ^ srow) * 8;     // pre-swizzled source granule

  // prologue: stage K-step 0 into buf 0
#pragma unroll
  for (int i = 0; i < 4; ++i) {
    int r0 = wv * 32 + i * 8;
    GLDS(X  + (M0 + r0 + srow) * D_ + sg, AB(0) + r0 * 64);
    GLDS(Wt + (N0 + r0 + srow) * D_ + sg, BB(0) + r0 * 64);
  }

  f32x4 acc[4][4];
#pragma unroll
  for (int mt = 0; mt < 4; mt++)
#pragma unroll
    for (int nt = 0; nt < 4; nt++) acc[mt][nt] = zero4();

  __syncthreads();   // drains vmcnt(0): step-0 tiles staged & visible

  for (int j = 0; j < 8; ++j) {
    int cb = j & 1;
    if (j < 7) {
      int k0 = (j + 1) * 64;
#pragma unroll
      for (int i = 0; i < 4; ++i) {
        int r0 = wv * 32 + i * 8;
        GLDS(X  + (M0 + r0 + srow) * D_ + k0 + sg, AB(cb ^ 1) + r0 * 64);
        GLDS(Wt + (N0 + r0 + srow) * D_ + k0 + sg, BB(cb ^ 1) + r0 * 64);
      }
    }
    const __bf16* Al = AB(cb);
    const __bf16* Bl = BB(cb);
#pragma unroll
    for (int kk = 0; kk < 2; ++kk) {
      int gp = ((kk * 4 + quad) ^ (lc & 7)) * 8;
      bf16x8 a[4], bb[4];
#pragma unroll
      for (int mt = 0; mt < 4; mt++)
        a[mt] = *(const bf16x8*)(Al + (wr * 64 + mt * 16 + lc) * 64 + gp);
#pragma unroll
      for (int nt = 0; nt < 4; nt++)
        bb[nt] = *(const bf16x8*)(Bl + (wc * 64 + nt * 16 + lc) * 64 + gp);
#pragma unroll
      for (int mt = 0; mt < 4; mt++)
#pragma unroll
        for (int nt = 0; nt < 4; nt++)
          acc[mt][nt] = mfma16(a[mt], bb[nt], acc[mt][nt]);
    }
    __syncthreads();   // all waves done reading buf cb; next tile staged & visible
  }

  // epilogue staging aliases smem (all waves are past the loop's final barrier)
  __bf16* vlds = smem + wv * (64 * 72);

  int h = n0 >> 6;                 // one head per wave tile
  int b = m0 >> 11, s0 = m0 & (S_ - 1);
  if (z < 2) {
    // stage row-major [s-row][a-col], then 128B-contiguous row stores
#pragma unroll
    for (int nt = 0; nt < 4; nt++) {
      int col = n0 + nt * 16 + lc;
      float bval = bias[col] * bscale;
#pragma unroll
      for (int mt = 0; mt < 4; mt++)
#pragma unroll
        for (int r = 0; r < 4; r++)
          vlds[(mt * 16 + quad * 4 + r) * 72 + nt * 16 + lc] = (__bf16)(acc[mt][nt][r] + bval);
    }
    __asm__ volatile("s_waitcnt lgkmcnt(0)" ::: "memory");
    __bf16* dst = (z == 0) ? Qb : Kb;
#pragma unroll
    for (int it = 0; it < 8; it++) {
      int row = it * 8 + (lane >> 3);
      int c8 = (lane & 7) * 8;
      bf16x8 vv = *(const bf16x8*)(vlds + row * 72 + c8);
      *(bf16x8*)(dst + ((b * H_ + h) * S_ + s0 + row) * A_ + c8) = vv;   // [B,H,S,A]
    }
  } else {
    // V: stage transposed [a-row][s-col] (packed b64 writes), coalesced [B,H,A,S] stores
#pragma unroll
    for (int nt = 0; nt < 4; nt++) {
      int col = n0 + nt * 16 + lc;
      float bval = bias[col];
#pragma unroll
      for (int mt = 0; mt < 4; mt++) {
        bf16x4 pk;
#pragma unroll
        for (int r = 0; r < 4; r++) pk[r] = (__bf16)(acc[mt][nt][r] + bval);
        *(bf16x4*)(vlds + (nt * 16 + lc) * 72 + mt * 16 + quad * 4) = pk;
      }
    }
    __asm__ volatile("s_waitcnt lgkmcnt(0)" ::: "memory");
#pragma unroll
    for (int it = 0; it < 8; it++) {
      int a_l = it * 8 + (lane >> 3);
      int s_l = (lane & 7) * 8;
      bf16x8 vvv = *(const bf16x8*)(vlds + a_l * 72 + s_l);
      *(bf16x8*)(Vtb + ((b * H_ + h) * A_ + a_l) * S_ + s0 + s_l) = vvv;
    }
  }
}

// ---------------- flash attention: paired strips, swapped-QK, shared K/V registers ----------
// Structure as round-8 winner (256 blocks, 8 waves, long strip p + short strip 15-p per block,
// shared K/V LDS stream, swapped mfma(K,Q) -> lane-local P rows, packed b64 P stores).
// This round: K and V fragments are loaded from LDS ONCE per tile into registers and shared by
// both q-groups (their LDS addresses were identical). V loads issue before the exp phase
// (overlap exp + P roundtrip instead of stalling after it); group2's QK (register-only MFMAs)
// fills the group1 lgkm-drain shadow. Cuts ~20% of the per-block LDS-op budget -- flash is
// LDS-throughput bound (per-unit ~240 LDS cycles x 34 units x 8 waves ~ 27 us/CU of the ~37).
// VGPR rises ~60 -> ~160: fine at 1 block/CU (512 thr, 2 waves/SIMD, 256 VGPR cap); spill
// guard = flash WRITE_SIZE must stay ~8.2 MB.
__global__ __launch_bounds__(512) void flash_kernel(const __bf16* __restrict__ Q,
                                                    const __bf16* __restrict__ K,
                                                    const __bf16* __restrict__ Vt,
                                                    __bf16* __restrict__ O) {
  int id = blockIdx.x;                    // 0..255
  int xcd = id & 7, slot = id >> 3;       // slot 0..31
  int p = slot >> 2;                      // pair 0..7
  int bh = xcd * 4 + (slot & 3);          // 4 bh per XCD: K+V L2-resident
  int lane = threadIdx.x & 63, wv = threadIdx.x >> 6;   // wv 0..7
  int quad = lane >> 4, lc = lane & 15;
  int R1 = p * 128 + wv * 16;             // group1 (long) first row for this wave
  int R2 = (15 - p) * 128 + wv * 16;      // group2 (short) first row
  int t0 = 2 * p, ntile = 32 - 2 * p;

  const __bf16* Qp = Q + bh * S_ * A_;   // [S][64]
  const __bf16* Kp = K + bh * S_ * A_;   // [S][64]
  const __bf16* Vp = Vt + bh * A_ * S_;  // [64][S]

  __shared__ __align__(16) __bf16 kvbuf[2][2][64][64];   // [buf][0=K,1=V][row][64] = 32 KiB
  __shared__ __align__(16) __bf16 plds_all[8][16][72];   // per-wave P staging (time-shared)
  __bf16* plds = &plds_all[wv][0][0];

  int srow = lane >> 3;                  // 0..7
  int sg = ((lane & 7) ^ srow) * 8;      // swizzled source granule
  int wr8 = wv * 8;                      // staging rows: 8 waves x 8 rows = 64

  // ---- prologue: stage tile t0 into buf0 ----
  {
    int kt = t0 << 6;
    GLDS(Kp + (kt + wr8 + srow) * A_ + sg, &kvbuf[0][0][wr8][0]);
    GLDS(Vp + (wr8 + srow) * S_ + kt + sg, &kvbuf[0][1][wr8][0]);
  }

  bf16x8 qf1[2], qf2[2];
  qf1[0] = *(const bf16x8*)(Qp + (R1 + lc) * A_ + quad * 8);
  qf1[1] = *(const bf16x8*)(Qp + (R1 + lc) * A_ + 32 + quad * 8);
  qf2[0] = *(const bf16x8*)(Qp + (R2 + lc) * A_ + quad * 8);
  qf2[1] = *(const bf16x8*)(Qp + (R2 + lc) * A_ + 32 + quad * 8);

  f32x4 o1[4], o2[4];
  float ls1 = 0.f, ls2 = 0.f;            // per-lane partial row-sum for q-row R+lc
#pragma unroll
  for (int t = 0; t < 4; t++) { o1[t] = zero4(); o2[t] = zero4(); }

  int g0 = (quad ^ (lc & 7)) * 8;        // swizzled granule offsets for frag reads
  int g1 = ((quad + 4) ^ (lc & 7)) * 8;

  __syncthreads();   // drains vmcnt(0): tile t0 staged & visible

  for (int j = 0; j < ntile; ++j) {
    int t = t0 + j;
    int cb = j & 1;
    if (j + 1 < ntile) {
      int ktn = (t + 1) << 6;
      GLDS(Kp + (ktn + wr8 + srow) * A_ + sg, &kvbuf[cb ^ 1][0][wr8][0]);
      GLDS(Vp + (wr8 + srow) * S_ + ktn + sg, &kvbuf[cb ^ 1][1][wr8][0]);
    }
    const __bf16* Kl = &kvbuf[cb][0][0][0];
    const __bf16* Vl = &kvbuf[cb][1][0][0];
    bool g2 = (t * 64 + 63 > R2);        // group2 active this tile

    // ---- K and V fragments: loaded ONCE, shared by both groups ----
    bf16x8 kf[4][2], vf[4][2];
#pragma unroll
    for (int nt = 0; nt < 4; nt++) {
      int rr = nt * 16 + lc;
      kf[nt][0] = *(const bf16x8*)(Kl + rr * 64 + g0);
      kf[nt][1] = *(const bf16x8*)(Kl + rr * 64 + g1);
    }
#pragma unroll
    for (int ot = 0; ot < 4; ot++) {
      int rr = ot * 16 + lc;
      vf[ot][0] = *(const bf16x8*)(Vl + rr * 64 + g0);  // issued early: latency hides under exp
      vf[ot][1] = *(const bf16x8*)(Vl + rr * 64 + g1);
    }

    // ---- group1 QK (swapped: C[q-row=lc][key=quad*4+r+16nt]) ----
    f32x4 sc[4];
#pragma unroll
    for (int nt = 0; nt < 4; nt++) {
      f32x4 ss = zero4();
      ss = mfma16(kf[nt][0], qf1[0], ss);
      ss = mfma16(kf[nt][1], qf1[1], ss);
      sc[nt] = ss;
    }
    // ---- group1 exp + packed P store ----
    if (t * 64 <= R1 + 15) {             // diagonal region: mask col <= row -> 0
      int row = R1 + lc;
#pragma unroll
      for (int nt = 0; nt < 4; nt++)
#pragma unroll
        for (int r = 0; r < 4; r++) {
          int col = t * 64 + nt * 16 + quad * 4 + r;
          float pv = (col <= row) ? 0.0f : EXP2(sc[nt][r]);
          ls1 += pv;
          sc[nt][r] = pv;
        }
    } else {
#pragma unroll
      for (int nt = 0; nt < 4; nt++)
#pragma unroll
        for (int r = 0; r < 4; r++) {
          float pv = EXP2(sc[nt][r]);
          ls1 += pv;
          sc[nt][r] = pv;
        }
    }
#pragma unroll
    for (int nt = 0; nt < 4; nt++) {
      bf16x4 pk;
#pragma unroll
      for (int r = 0; r < 4; r++) pk[r] = (__bf16)sc[nt][r];
      *(bf16x4*)(plds + lc * 72 + nt * 16 + quad * 4) = pk;
    }
    // ---- group2 QK from registers (fills the lgkm-drain shadow; no LDS) ----
    f32x4 sc2[4];
    if (g2) {
#pragma unroll
      for (int nt = 0; nt < 4; nt++) {
        f32x4 ss = zero4();
        ss = mfma16(kf[nt][0], qf2[0], ss);
        ss = mfma16(kf[nt][1], qf2[1], ss);
        sc2[nt] = ss;
      }
    }
    __asm__ volatile("s_waitcnt lgkmcnt(0)" ::: "memory");
    {
      bf16x8 pf0 = *(const bf16x8*)(plds + lc * 72 + quad * 8);
      bf16x8 pf1 = *(const bf16x8*)(plds + lc * 72 + 32 + quad * 8);
      __builtin_amdgcn_s_setprio(1);
#pragma unroll
      for (int ot = 0; ot < 4; ot++) {
        o1[ot] = mfma16(pf0, vf[ot][0], o1[ot]);
        o1[ot] = mfma16(pf1, vf[ot][1], o1[ot]);
      }
      __builtin_amdgcn_s_setprio(0);
    }

    // ---- group2 exp + P + PV (K/V from registers) ----
    if (g2) {
      if (t * 64 <= R2 + 15) {
        int row = R2 + lc;
#pragma unroll
        for (int nt = 0; nt < 4; nt++)
#pragma unroll
          for (int r = 0; r < 4; r++) {
            int col = t * 64 + nt * 16 + quad * 4 + r;
            float pv = (col <= row) ? 0.0f : EXP2(sc2[nt][r]);
            ls2 += pv;
            sc2[nt][r] = pv;
          }
      } else {
#pragma unroll
        for (int nt = 0; nt < 4; nt++)
#pragma unroll
          for (int r = 0; r < 4; r++) {
            float pv = EXP2(sc2[nt][r]);
            ls2 += pv;
            sc2[nt][r] = pv;
          }
      }
#pragma unroll
      for (int nt = 0; nt < 4; nt++) {
        bf16x4 pk;
#pragma unroll
        for (int r = 0; r < 4; r++) pk[r] = (__bf16)sc2[nt][r];
        *(bf16x4*)(plds + lc * 72 + nt * 16 + quad * 4) = pk;
      }
      __asm__ volatile("s_waitcnt lgkmcnt(0)" ::: "memory");
      bf16x8 pf0 = *(const bf16x8*)(plds + lc * 72 + quad * 8);
      bf16x8 pf1 = *(const bf16x8*)(plds + lc * 72 + 32 + quad * 8);
      __builtin_amdgcn_s_setprio(1);
#pragma unroll
      for (int ot = 0; ot < 4; ot++) {
        o2[ot] = mfma16(pf0, vf[ot][0], o2[ot]);
        o2[ot] = mfma16(pf1, vf[ot][1], o2[ot]);
      }
      __builtin_amdgcn_s_setprio(0);
    }
    __syncthreads();   // all waves done reading buf cb; next tile staged & visible
  }

  // ---- complete row-sums: combine the 4 quads holding partials for row lc ----
  ls1 += __shfl_xor(ls1, 16, 64);
  ls1 += __shfl_xor(ls1, 32, 64);
  ls2 += __shfl_xor(ls2, 16, 64);
  ls2 += __shfl_xor(ls2, 32, 64);
  // per-lane denominators for epilogue rows quad*4+r (broadcast from lane holding that row)
  float rl1[4], rl2[4];
#pragma unroll
  for (int r = 0; r < 4; r++) {
    rl1[r] = 1.0f / __shfl(ls1, quad * 4 + r, 64);
    rl2[r] = 1.0f / __shfl(ls2, quad * 4 + r, 64);
  }

  int b = bh >> 3, h = bh & 7;

  // ---- epilogue group 1: normalize into per-wave LDS tile, 16B coalesced stores ----
#pragma unroll
  for (int r = 0; r < 4; r++)
#pragma unroll
    for (int ot = 0; ot < 4; ot++)
      plds[(quad * 4 + r) * 72 + ot * 16 + lc] = (__bf16)(o1[ot][r] * rl1[r]);
  __asm__ volatile("s_waitcnt lgkmcnt(0)" ::: "memory");
#pragma unroll
  for (int it = 0; it < 2; it++) {
    int row = it * 8 + (lane >> 3);
    int c8 = (lane & 7) * 8;
    *(bf16x8*)(O + (b * S_ + R1 + row) * (H_ * A_) + h * 64 + c8) =
        *(const bf16x8*)(plds + row * 72 + c8);
  }

  // ---- epilogue group 2 (skip row 2047: NaN from 1/0; p==7 block rewrites it) ----
#pragma unroll
  for (int r = 0; r < 4; r++)
#pragma unroll
    for (int ot = 0; ot < 4; ot++)
      plds[(quad * 4 + r) * 72 + ot * 16 + lc] = (__bf16)(o2[ot][r] * rl2[r]);
  __asm__ volatile("s_waitcnt lgkmcnt(0)" ::: "memory");
#pragma unroll
  for (int it = 0; it < 2; it++) {
    int row = it * 8 + (lane >> 3);
    int c8 = (lane & 7) * 8;
    int grow = R2 + row;
    if (grow != S_ - 1)
      *(bf16x8*)(O + (b * S_ + grow) * (H_ * A_) + h * 64 + c8) =
          *(const bf16x8*)(plds + row * 72 + c8);
  }

  // ---- fused row-2047 fix: softmax over all -1e9 is uniform -> O = mean(V) ----
  if (p == 7) {
    int a = threadIdx.x >> 3;       // 0..63
    int li = threadIdx.x & 7;       // 8 lanes per a-row
    const __bf16* src = Vp + a * S_;
    float ssum = 0.f;
#pragma unroll 8
    for (int j2 = 0; j2 < 32; j2++) {
      bf16x8 vv = *(const bf16x8*)(src + (j2 * 8 + li) * 8);
#pragma unroll
      for (int e = 0; e < 8; e++) ssum += (float)vv[e];
    }
    ssum += __shfl_xor(ssum, 1, 64);
    ssum += __shfl_xor(ssum, 2, 64);
    ssum += __shfl_xor(ssum, 4, 64);
    if (li == 0)
      O[(b * S_ + (S_ - 1)) * (H_ * A_) + h * 64 + a] = (__bf16)(ssum * (1.0f / 2048.0f));
  }
}

// ---------------- output projection: [8192x512] @ [512x512] + bo, fp32 out ----------------
// Same LDS-staged BK=64 double-buffered main loop as proj_gemm; direct fp32 epilogue stores.
__global__ __launch_bounds__(256) void out_gemm_kernel(const __bf16* __restrict__ Ob,
                                                       const __bf16* __restrict__ Wot,
                                                       const float* __restrict__ bo,
                                                       float* __restrict__ out) {
  int lane = threadIdx.x & 63, wv = threadIdx.x >> 6;
  int wr = wv >> 1, wc = wv & 1;
  int quad = lane >> 4, lc = lane & 15;
  int M0 = blockIdx.x * 128, N0 = blockIdx.y * 128;
  int m0 = M0 + wr * 64, n0 = N0 + wc * 64;

  __shared__ __align__(16) __bf16 smem[2 * 2 * 128 * 64];

  int srow = lane >> 3;
  int sg = ((lane & 7) ^ srow) * 8;

#pragma unroll
  for (int i = 0; i < 4; ++i) {
    int r0 = wv * 32 + i * 8;
    GLDS(Ob  + (M0 + r0 + srow) * D_ + sg, AB(0) + r0 * 64);
    GLDS(Wot + (N0 + r0 + srow) * D_ + sg, BB(0) + r0 * 64);
  }

  f32x4 acc[4][4];
#pragma unroll
  for (int mt = 0; mt < 4; mt++)
#pragma unroll
    for (int nt = 0; nt < 4; nt++) acc[mt][nt] = zero4();

  __syncthreads();

  for (int j = 0; j < 8; ++j) {
    int cb = j & 1;
    if (j < 7) {
      int k0 = (j + 1) * 64;
#pragma unroll
      for (int i = 0; i < 4; ++i) {
        int r0 = wv * 32 + i * 8;
        GLDS(Ob  + (M0 + r0 + srow) * D_ + k0 + sg, AB(cb ^ 1) + r0 * 64);
        GLDS(Wot + (N0 + r0 + srow) * D_ + k0 + sg, BB(cb ^ 1) + r0 * 64);
      }
    }
    const __bf16* Al = AB(cb);
    const __bf16* Bl = BB(cb);
#pragma unroll
    for (int kk = 0; kk < 2; ++kk) {
      int gp = ((kk * 4 + quad) ^ (lc & 7)) * 8;
      bf16x8 a[4], bb[4];
#pragma unroll
      for (int mt = 0; mt < 4; mt++)
        a[mt] = *(const bf16x8*)(Al + (wr * 64 + mt * 16 + lc) * 64 + gp);
#pragma unroll
      for (int nt = 0; nt < 4; nt++)
        bb[nt] = *(const bf16x8*)(Bl + (wc * 64 + nt * 16 + lc) * 64 + gp);
#pragma unroll
      for (int mt = 0; mt < 4; mt++)
#pragma unroll
        for (int nt = 0; nt < 4; nt++)
          acc[mt][nt] = mfma16(a[mt], bb[nt], acc[mt][nt]);
    }
    __syncthreads();
  }

#pragma unroll
  for (int nt = 0; nt < 4; nt++) {
    int col = n0 + nt * 16 + lc;
    float bval = bo[col];
#pragma unroll
    for (int mt = 0; mt < 4; mt++)
#pragma unroll
      for (int r = 0; r < 4; r++) {
        int row = m0 + mt * 16 + quad * 4 + r;
        out[row * D_ + col] = acc[mt][nt][r] + bval;
      }
  }
}

extern "C" void kernel_launch(void* const* d_in, const int* in_sizes, int n_in,
                              void* d_out, int out_size, void* d_ws, size_t ws_size,
                              hipStream_t stream) {
  const float* q  = (const float*)d_in[0];
  const float* k  = (const float*)d_in[1];
  const float* v  = (const float*)d_in[2];
  const float* Wq = (const float*)d_in[3];
  const float* bq = (const float*)d_in[4];
  const float* Wk = (const float*)d_in[5];
  const float* bk = (const float*)d_in[6];
  const float* Wv = (const float*)d_in[7];
  const float* bv = (const float*)d_in[8];
  const float* Wo = (const float*)d_in[9];
  const float* bo = (const float*)d_in[10];

  char* ws = (char*)d_ws;
  __bf16* Xq  = (__bf16*)(ws + 0);          // 8 MiB each
  __bf16* Xk  = (__bf16*)(ws + 8388608);
  __bf16* Xv  = (__bf16*)(ws + 16777216);
  __bf16* Wtq = (__bf16*)(ws + 25165824);   // 512 KiB each
  __bf16* Wtk = (__bf16*)(ws + 25690112);
  __bf16* Wtv = (__bf16*)(ws + 26214400);
  __bf16* Wot = (__bf16*)(ws + 26738688);
  __bf16* Qb  = (__bf16*)(ws + 27262976);   // 8 MiB each
  __bf16* Kb  = (__bf16*)(ws + 35651584);
  __bf16* Vtb = (__bf16*)(ws + 44040192);
  __bf16* Ob  = (__bf16*)(ws + 52428800);

  prep_all_kernel<<<12544, 256, 0, stream>>>(q, k, v, Wq, Wk, Wv, Wo,
                                             Xq, Xk, Xv, Wtq, Wtk, Wtv, Wot);
  proj_gemm_kernel<<<dim3(64, 4, 3), 256, 0, stream>>>(Xq, Xk, Xv, Wtq, Wtk, Wtv,
                                                       bq, bk, bv, Qb, Kb, Vtb);
  flash_kernel<<<dim3(256), 512, 0, stream>>>(Qb, Kb, Vtb, Ob);
  out_gemm_kernel<<<dim3(64, 4), 256, 0, stream>>>(Ob, Wot, bo, (float*)d_out);
}

// Round 10
// 173.052 us; speedup vs baseline: 1.0148x; 1.0148x over previous
//
#include <hip/hip_runtime.h>
#include <hip/hip_bf16.h>

#define B_ 4
#define S_ 2048
#define D_ 512
#define H_ 8
#define A_ 64

typedef __attribute__((ext_vector_type(8))) __bf16 bf16x8;
typedef __attribute__((ext_vector_type(4))) __bf16 bf16x4;
typedef __attribute__((ext_vector_type(4))) float f32x4;

static __device__ __forceinline__ f32x4 mfma16(bf16x8 a, bf16x8 b, f32x4 c) {
  return __builtin_amdgcn_mfma_f32_16x16x32_bf16(a, b, c, 0, 0, 0);
}

static __device__ __forceinline__ f32x4 zero4() {
  f32x4 z = {0.f, 0.f, 0.f, 0.f};
  return z;
}

// 0.125 (1/sqrt(A)) * log2(e): scores are consumed by v_exp (2^x) in flash_kernel
#define QSCALE 0.18033688011f

#if __has_builtin(__builtin_amdgcn_exp2f)
#define EXP2(x) __builtin_amdgcn_exp2f(x)
#else
#define EXP2(x) exp2f(x)
#endif

// async global->LDS, 16B per lane, lds dest = wave-uniform base + lane*16
#define GLDS(g, l)                                                      \
  __builtin_amdgcn_global_load_lds(                                     \
      (const __attribute__((address_space(1))) void*)(g),               \
      (__attribute__((address_space(3))) void*)(l), 16, 0, 0)

// ------------- merged input prep: fp32->bf16 activations + LDS-transposed weights -------------
__global__ void prep_all_kernel(const float* __restrict__ q, const float* __restrict__ k,
                                const float* __restrict__ v,
                                const float* __restrict__ Wq, const float* __restrict__ Wk,
                                const float* __restrict__ Wv, const float* __restrict__ Wo,
                                __bf16* __restrict__ xq, __bf16* __restrict__ xk,
                                __bf16* __restrict__ xv,
                                __bf16* __restrict__ tq, __bf16* __restrict__ tk,
                                __bf16* __restrict__ tv, __bf16* __restrict__ to_) {
  __shared__ float tile[64][65];
  if (blockIdx.x < 12288) {
    int idx = blockIdx.x * 256 + threadIdx.x;  // 3 * 2^20 threads, one float4 each
    int which = idx >> 20;
    int i = idx & ((1 << 20) - 1);
    const float4* s = (const float4*)(which == 0 ? q : (which == 1 ? k : v));
    __bf16* d = (which == 0) ? xq : (which == 1 ? xk : xv);
    float4 f = s[i];
    bf16x4 o;
    o.x = (__bf16)f.x; o.y = (__bf16)f.y; o.z = (__bf16)f.z; o.w = (__bf16)f.w;
    *(bf16x4*)(d + 4 * i) = o;
  } else {
    int t = blockIdx.x - 12288;   // 0..255
    if (t < 192) {
      // Wq/Wk/Wv: tq[n=h*64+a][k=d] = W[h][d][a] (coalesced both sides via LDS transpose)
      int mat = t >> 6;
      int h = (t >> 3) & 7;
      int d0 = (t & 7) * 64;
      const float* W = (mat == 0) ? Wq : (mat == 1 ? Wk : Wv);
      __bf16* dst = (mat == 0) ? tq : (mat == 1 ? tk : tv);
      float sc = (mat == 0) ? QSCALE : 1.0f;   // fold 1/sqrt(A)*log2e into Q projection
      int a = threadIdx.x & 63, r0 = threadIdx.x >> 6;
#pragma unroll
      for (int i = 0; i < 16; i++) {
        int dd = r0 * 16 + i;
        tile[dd][a] = W[(h * D_ + d0 + dd) * A_ + a] * sc;
      }
      __syncthreads();
      int dd = threadIdx.x & 63, a0 = threadIdx.x >> 6;
#pragma unroll
      for (int i = 0; i < 16; i++) {
        int a2 = a0 * 16 + i;
        dst[(h * 64 + a2) * D_ + d0 + dd] = (__bf16)tile[dd][a2];
      }
    } else {
      // Wo: Wot[n=d][k=f] = Wo[f][d]
      int t2 = t - 192;           // 0..63
      int f0 = (t2 >> 3) * 64, d0 = (t2 & 7) * 64;
      int d = threadIdx.x & 63, r0 = threadIdx.x >> 6;
#pragma unroll
      for (int i = 0; i < 16; i++) {
        int ff = r0 * 16 + i;
        tile[ff][d] = Wo[(f0 + ff) * D_ + d0 + d];
      }
      __syncthreads();
      int f = threadIdx.x & 63, a0 = threadIdx.x >> 6;
#pragma unroll
      for (int i = 0; i < 16; i++) {
        int dd = a0 * 16 + i;
        to_[(d0 + dd) * D_ + f0 + f] = (__bf16)tile[f][dd];
      }
    }
  }
}

// ---------------- QKV projection GEMM: [8192x512] @ [512x512] per matrix ----------------
// 128x128 tile, 4 waves 2x2, BK=64, double-buffered global_load_lds staging (16B-granule XOR
// swizzle on both sides). Round-4 verified.
__global__ __launch_bounds__(256) void proj_gemm_kernel(
    const __bf16* __restrict__ Xq, const __bf16* __restrict__ Xk, const __bf16* __restrict__ Xv,
    const __bf16* __restrict__ Wtq, const __bf16* __restrict__ Wtk, const __bf16* __restrict__ Wtv,
    const float* __restrict__ bq, const float* __restrict__ bk, const float* __restrict__ bv,
    __bf16* __restrict__ Qb, __bf16* __restrict__ Kb, __bf16* __restrict__ Vtb) {
  int z = blockIdx.z;
  const __bf16* X  = (z == 0) ? Xq  : (z == 1 ? Xk  : Xv);
  const __bf16* Wt = (z == 0) ? Wtq : (z == 1 ? Wtk : Wtv);
  const float* bias = (z == 0) ? bq : (z == 1 ? bk : bv);
  float bscale = (z == 0) ? QSCALE : 1.0f;

  int lane = threadIdx.x & 63, wv = threadIdx.x >> 6;
  int wr = wv >> 1, wc = wv & 1;
  int quad = lane >> 4, lc = lane & 15;
  int M0 = blockIdx.x * 128, N0 = blockIdx.y * 128;
  int m0 = M0 + wr * 64, n0 = N0 + wc * 64;

  // 64 KiB: [buf][A|B][128][64]; epilogue staging aliases this after the loop
  __shared__ __align__(16) __bf16 smem[2 * 2 * 128 * 64];
#define AB(buf) (smem + (buf) * 16384)
#define BB(buf) (smem + (buf) * 16384 + 8192)

  int srow = lane >> 3;                 // 0..7
  int sg = ((lane & 7) ^ srow) * 8;     // pre-swizzled source granule

  // prologue: stage K-step 0 into buf 0
#pragma unroll
  for (int i = 0; i < 4; ++i) {
    int r0 = wv * 32 + i * 8;
    GLDS(X  + (M0 + r0 + srow) * D_ + sg, AB(0) + r0 * 64);
    GLDS(Wt + (N0 + r0 + srow) * D_ + sg, BB(0) + r0 * 64);
  }

  f32x4 acc[4][4];
#pragma unroll
  for (int mt = 0; mt < 4; mt++)
#pragma unroll
    for (int nt = 0; nt < 4; nt++) acc[mt][nt] = zero4();

  __syncthreads();   // drains vmcnt(0): step-0 tiles staged & visible

  for (int j = 0; j < 8; ++j) {
    int cb = j & 1;
    if (j < 7) {
      int k0 = (j + 1) * 64;
#pragma unroll
      for (int i = 0; i < 4; ++i) {
        int r0 = wv * 32 + i * 8;
        GLDS(X  + (M0 + r0 + srow) * D_ + k0 + sg, AB(cb ^ 1) + r0 * 64);
        GLDS(Wt + (N0 + r0 + srow) * D_ + k0 + sg, BB(cb ^ 1) + r0 * 64);
      }
    }
    const __bf16* Al = AB(cb);
    const __bf16* Bl = BB(cb);
#pragma unroll
    for (int kk = 0; kk < 2; ++kk) {
      int gp = ((kk * 4 + quad) ^ (lc & 7)) * 8;
      bf16x8 a[4], bb[4];
#pragma unroll
      for (int mt = 0; mt < 4; mt++)
        a[mt] = *(const bf16x8*)(Al + (wr * 64 + mt * 16 + lc) * 64 + gp);
#pragma unroll
      for (int nt = 0; nt < 4; nt++)
        bb[nt] = *(const bf16x8*)(Bl + (wc * 64 + nt * 16 + lc) * 64 + gp);
#pragma unroll
      for (int mt = 0; mt < 4; mt++)
#pragma unroll
        for (int nt = 0; nt < 4; nt++)
          acc[mt][nt] = mfma16(a[mt], bb[nt], acc[mt][nt]);
    }
    __syncthreads();   // all waves done reading buf cb; next tile staged & visible
  }

  // epilogue staging aliases smem (all waves are past the loop's final barrier)
  __bf16* vlds = smem + wv * (64 * 72);

  int h = n0 >> 6;                 // one head per wave tile
  int b = m0 >> 11, s0 = m0 & (S_ - 1);
  if (z < 2) {
    // stage row-major [s-row][a-col], then 128B-contiguous row stores
#pragma unroll
    for (int nt = 0; nt < 4; nt++) {
      int col = n0 + nt * 16 + lc;
      float bval = bias[col] * bscale;
#pragma unroll
      for (int mt = 0; mt < 4; mt++)
#pragma unroll
        for (int r = 0; r < 4; r++)
          vlds[(mt * 16 + quad * 4 + r) * 72 + nt * 16 + lc] = (__bf16)(acc[mt][nt][r] + bval);
    }
    __asm__ volatile("s_waitcnt lgkmcnt(0)" ::: "memory");
    __bf16* dst = (z == 0) ? Qb : Kb;
#pragma unroll
    for (int it = 0; it < 8; it++) {
      int row = it * 8 + (lane >> 3);
      int c8 = (lane & 7) * 8;
      bf16x8 vv = *(const bf16x8*)(vlds + row * 72 + c8);
      *(bf16x8*)(dst + ((b * H_ + h) * S_ + s0 + row) * A_ + c8) = vv;   // [B,H,S,A]
    }
  } else {
    // V: stage transposed [a-row][s-col] (packed b64 writes), coalesced [B,H,A,S] stores
#pragma unroll
    for (int nt = 0; nt < 4; nt++) {
      int col = n0 + nt * 16 + lc;
      float bval = bias[col];
#pragma unroll
      for (int mt = 0; mt < 4; mt++) {
        bf16x4 pk;
#pragma unroll
        for (int r = 0; r < 4; r++) pk[r] = (__bf16)(acc[mt][nt][r] + bval);
        *(bf16x4*)(vlds + (nt * 16 + lc) * 72 + mt * 16 + quad * 4) = pk;
      }
    }
    __asm__ volatile("s_waitcnt lgkmcnt(0)" ::: "memory");
#pragma unroll
    for (int it = 0; it < 8; it++) {
      int a_l = it * 8 + (lane >> 3);
      int s_l = (lane & 7) * 8;
      bf16x8 vvv = *(const bf16x8*)(vlds + a_l * 72 + s_l);
      *(bf16x8*)(Vtb + ((b * H_ + h) * A_ + a_l) * S_ + s0 + s_l) = vvv;
    }
  }
}

// ---------------- flash attention: paired strips, swapped-QK, 2 independent blocks/CU ------
// Round-10 change: split each 8-wave block into TWO 4-wave blocks (512 blocks, 2/CU), block =
// (bh, pair p, half): rows p*128+half*64 (long group) + (15-p)*128+half*64 (short group),
// 16 rows per wave as before. Per-block work stays ~constant (34/32 units) -> dispatch-map
// independent. Rationale: flash is chain+barrier-drain bound -- every tile ends in
// __syncthreads whose vmcnt(0) drain (~500cy) idles the whole CU at 1 block/CU. Two blocks
// with INDEPENDENT barriers and K/V streams overlap: one block's MFMA/VALU fills the other's
// drain. LDS 2 x 41 KB = 84 KB/CU; 8 waves/CU unchanged. Spill guard: WRITE_SIZE ~8.2 MB.
// Keeps round-8/9 body: swapped mfma(K,Q) lane-local P, packed b64 P stores, shared K/V regs.
__global__ __launch_bounds__(256) void flash_kernel(const __bf16* __restrict__ Q,
                                                    const __bf16* __restrict__ K,
                                                    const __bf16* __restrict__ Vt,
                                                    __bf16* __restrict__ O) {
  int id = blockIdx.x;                    // 0..511
  int xcd = id & 7, slot = id >> 3;       // slot 0..63
  int half = slot >> 5;                   // 0,1: which 64-row half of each strip
  int p = (slot >> 2) & 7;                // pair 0..7
  int bh = xcd * 4 + (slot & 3);          // 4 bh per XCD: K+V L2-resident
  int lane = threadIdx.x & 63, wv = threadIdx.x >> 6;   // wv 0..3
  int quad = lane >> 4, lc = lane & 15;
  int R1 = p * 128 + half * 64 + wv * 16;         // group1 (long) first row for this wave
  int R2 = (15 - p) * 128 + half * 64 + wv * 16;  // group2 (short) first row
  int t0 = 2 * p + half, ntile = 32 - t0;

  const __bf16* Qp = Q + bh * S_ * A_;   // [S][64]
  const __bf16* Kp = K + bh * S_ * A_;   // [S][64]
  const __bf16* Vp = Vt + bh * A_ * S_;  // [64][S]

  __shared__ __align__(16) __bf16 kvbuf[2][2][64][64];   // [buf][0=K,1=V][row][64] = 32 KiB
  __shared__ __align__(16) __bf16 plds_all[4][16][72];   // per-wave P staging (time-shared)
  __bf16* plds = &plds_all[wv][0][0];

  int srow = lane >> 3;                  // 0..7
  int sg = ((lane & 7) ^ srow) * 8;      // swizzled source granule
  int wr16 = wv * 16;                    // staging rows: 4 waves x 16 rows = 64

  // ---- prologue: stage tile t0 into buf0 ----
  {
    int kt = t0 << 6;
#pragma unroll
    for (int i = 0; i < 2; ++i) {
      int r0 = wr16 + i * 8;
      GLDS(Kp + (kt + r0 + srow) * A_ + sg, &kvbuf[0][0][r0][0]);
      GLDS(Vp + (r0 + srow) * S_ + kt + sg, &kvbuf[0][1][r0][0]);
    }
  }

  bf16x8 qf1[2], qf2[2];
  qf1[0] = *(const bf16x8*)(Qp + (R1 + lc) * A_ + quad * 8);
  qf1[1] = *(const bf16x8*)(Qp + (R1 + lc) * A_ + 32 + quad * 8);
  qf2[0] = *(const bf16x8*)(Qp + (R2 + lc) * A_ + quad * 8);
  qf2[1] = *(const bf16x8*)(Qp + (R2 + lc) * A_ + 32 + quad * 8);

  f32x4 o1[4], o2[4];
  float ls1 = 0.f, ls2 = 0.f;            // per-lane partial row-sum for q-row R+lc
#pragma unroll
  for (int t = 0; t < 4; t++) { o1[t] = zero4(); o2[t] = zero4(); }

  int g0 = (quad ^ (lc & 7)) * 8;        // swizzled granule offsets for frag reads
  int g1 = ((quad + 4) ^ (lc & 7)) * 8;

  __syncthreads();   // drains vmcnt(0): tile t0 staged & visible

  for (int j = 0; j < ntile; ++j) {
    int t = t0 + j;
    int cb = j & 1;
    if (j + 1 < ntile) {
      int ktn = (t + 1) << 6;
#pragma unroll
      for (int i = 0; i < 2; ++i) {
        int r0 = wr16 + i * 8;
        GLDS(Kp + (ktn + r0 + srow) * A_ + sg, &kvbuf[cb ^ 1][0][r0][0]);
        GLDS(Vp + (r0 + srow) * S_ + ktn + sg, &kvbuf[cb ^ 1][1][r0][0]);
      }
    }
    const __bf16* Kl = &kvbuf[cb][0][0][0];
    const __bf16* Vl = &kvbuf[cb][1][0][0];
    bool g2 = (t * 64 + 63 > R2);        // group2 active this tile

    // ---- K and V fragments: loaded ONCE, shared by both groups ----
    bf16x8 kf[4][2], vf[4][2];
#pragma unroll
    for (int nt = 0; nt < 4; nt++) {
      int rr = nt * 16 + lc;
      kf[nt][0] = *(const bf16x8*)(Kl + rr * 64 + g0);
      kf[nt][1] = *(const bf16x8*)(Kl + rr * 64 + g1);
    }
#pragma unroll
    for (int ot = 0; ot < 4; ot++) {
      int rr = ot * 16 + lc;
      vf[ot][0] = *(const bf16x8*)(Vl + rr * 64 + g0);  // issued early: latency hides under exp
      vf[ot][1] = *(const bf16x8*)(Vl + rr * 64 + g1);
    }

    // ---- group1 QK (swapped: C[q-row=lc][key=quad*4+r+16nt]) ----
    f32x4 sc[4];
#pragma unroll
    for (int nt = 0; nt < 4; nt++) {
      f32x4 ss = zero4();
      ss = mfma16(kf[nt][0], qf1[0], ss);
      ss = mfma16(kf[nt][1], qf1[1], ss);
      sc[nt] = ss;
    }
    // ---- group1 exp + packed P store ----
    if (t * 64 <= R1 + 15) {             // diagonal region: mask col <= row -> 0
      int row = R1 + lc;
#pragma unroll
      for (int nt = 0; nt < 4; nt++)
#pragma unroll
        for (int r = 0; r < 4; r++) {
          int col = t * 64 + nt * 16 + quad * 4 + r;
          float pv = (col <= row) ? 0.0f : EXP2(sc[nt][r]);
          ls1 += pv;
          sc[nt][r] = pv;
        }
    } else {
#pragma unroll
      for (int nt = 0; nt < 4; nt++)
#pragma unroll
        for (int r = 0; r < 4; r++) {
          float pv = EXP2(sc[nt][r]);
          ls1 += pv;
          sc[nt][r] = pv;
        }
    }
#pragma unroll
    for (int nt = 0; nt < 4; nt++) {
      bf16x4 pk;
#pragma unroll
      for (int r = 0; r < 4; r++) pk[r] = (__bf16)sc[nt][r];
      *(bf16x4*)(plds + lc * 72 + nt * 16 + quad * 4) = pk;
    }
    // ---- group2 QK from registers (fills the lgkm-drain shadow; no LDS) ----
    f32x4 sc2[4];
    if (g2) {
#pragma unroll
      for (int nt = 0; nt < 4; nt++) {
        f32x4 ss = zero4();
        ss = mfma16(kf[nt][0], qf2[0], ss);
        ss = mfma16(kf[nt][1], qf2[1], ss);
        sc2[nt] = ss;
      }
    }
    __asm__ volatile("s_waitcnt lgkmcnt(0)" ::: "memory");
    {
      bf16x8 pf0 = *(const bf16x8*)(plds + lc * 72 + quad * 8);
      bf16x8 pf1 = *(const bf16x8*)(plds + lc * 72 + 32 + quad * 8);
      __builtin_amdgcn_s_setprio(1);
#pragma unroll
      for (int ot = 0; ot < 4; ot++) {
        o1[ot] = mfma16(pf0, vf[ot][0], o1[ot]);
        o1[ot] = mfma16(pf1, vf[ot][1], o1[ot]);
      }
      __builtin_amdgcn_s_setprio(0);
    }

    // ---- group2 exp + P + PV (K/V from registers) ----
    if (g2) {
      if (t * 64 <= R2 + 15) {
        int row = R2 + lc;
#pragma unroll
        for (int nt = 0; nt < 4; nt++)
#pragma unroll
          for (int r = 0; r < 4; r++) {
            int col = t * 64 + nt * 16 + quad * 4 + r;
            float pv = (col <= row) ? 0.0f : EXP2(sc2[nt][r]);
            ls2 += pv;
            sc2[nt][r] = pv;
          }
      } else {
#pragma unroll
        for (int nt = 0; nt < 4; nt++)
#pragma unroll
          for (int r = 0; r < 4; r++) {
            float pv = EXP2(sc2[nt][r]);
            ls2 += pv;
            sc2[nt][r] = pv;
          }
      }
#pragma unroll
      for (int nt = 0; nt < 4; nt++) {
        bf16x4 pk;
#pragma unroll
        for (int r = 0; r < 4; r++) pk[r] = (__bf16)sc2[nt][r];
        *(bf16x4*)(plds + lc * 72 + nt * 16 + quad * 4) = pk;
      }
      __asm__ volatile("s_waitcnt lgkmcnt(0)" ::: "memory");
      bf16x8 pf0 = *(const bf16x8*)(plds + lc * 72 + quad * 8);
      bf16x8 pf1 = *(const bf16x8*)(plds + lc * 72 + 32 + quad * 8);
      __builtin_amdgcn_s_setprio(1);
#pragma unroll
      for (int ot = 0; ot < 4; ot++) {
        o2[ot] = mfma16(pf0, vf[ot][0], o2[ot]);
        o2[ot] = mfma16(pf1, vf[ot][1], o2[ot]);
      }
      __builtin_amdgcn_s_setprio(0);
    }
    __syncthreads();   // all waves done reading buf cb; next tile staged & visible
  }

  // ---- complete row-sums: combine the 4 quads holding partials for row lc ----
  ls1 += __shfl_xor(ls1, 16, 64);
  ls1 += __shfl_xor(ls1, 32, 64);
  ls2 += __shfl_xor(ls2, 16, 64);
  ls2 += __shfl_xor(ls2, 32, 64);
  // per-lane denominators for epilogue rows quad*4+r (broadcast from lane holding that row)
  float rl1[4], rl2[4];
#pragma unroll
  for (int r = 0; r < 4; r++) {
    rl1[r] = 1.0f / __shfl(ls1, quad * 4 + r, 64);
    rl2[r] = 1.0f / __shfl(ls2, quad * 4 + r, 64);
  }

  int b = bh >> 3, h = bh & 7;

  // ---- epilogue group 1: normalize into per-wave LDS tile, 16B coalesced stores ----
#pragma unroll
  for (int r = 0; r < 4; r++)
#pragma unroll
    for (int ot = 0; ot < 4; ot++)
      plds[(quad * 4 + r) * 72 + ot * 16 + lc] = (__bf16)(o1[ot][r] * rl1[r]);
  __asm__ volatile("s_waitcnt lgkmcnt(0)" ::: "memory");
#pragma unroll
  for (int it = 0; it < 2; it++) {
    int row = it * 8 + (lane >> 3);
    int c8 = (lane & 7) * 8;
    *(bf16x8*)(O + (b * S_ + R1 + row) * (H_ * A_) + h * 64 + c8) =
        *(const bf16x8*)(plds + row * 72 + c8);
  }

  // ---- epilogue group 2 (skip row 2047: NaN from 1/0; rowfix block rewrites it) ----
#pragma unroll
  for (int r = 0; r < 4; r++)
#pragma unroll
    for (int ot = 0; ot < 4; ot++)
      plds[(quad * 4 + r) * 72 + ot * 16 + lc] = (__bf16)(o2[ot][r] * rl2[r]);
  __asm__ volatile("s_waitcnt lgkmcnt(0)" ::: "memory");
#pragma unroll
  for (int it = 0; it < 2; it++) {
    int row = it * 8 + (lane >> 3);
    int c8 = (lane & 7) * 8;
    int grow = R2 + row;
    if (grow != S_ - 1)
      *(bf16x8*)(O + (b * S_ + grow) * (H_ * A_) + h * 64 + c8) =
          *(const bf16x8*)(plds + row * 72 + c8);
  }

  // ---- fused row-2047 fix: softmax over all -1e9 is uniform -> O = mean(V) ----
  if (p == 7 && half == 0) {
    int a = threadIdx.x >> 2;       // 0..63
    int li = threadIdx.x & 3;       // 4 lanes per a-row
    const __bf16* src = Vp + a * S_;
    float ssum = 0.f;
#pragma unroll 8
    for (int j2 = 0; j2 < 64; j2++) {
      bf16x8 vv = *(const bf16x8*)(src + (j2 * 4 + li) * 8);
#pragma unroll
      for (int e = 0; e < 8; e++) ssum += (float)vv[e];
    }
    ssum += __shfl_xor(ssum, 1, 64);
    ssum += __shfl_xor(ssum, 2, 64);
    if (li == 0)
      O[(b * S_ + (S_ - 1)) * (H_ * A_) + h * 64 + a] = (__bf16)(ssum * (1.0f / 2048.0f));
  }
}

// ---------------- output projection: [8192x512] @ [512x512] + bo, fp32 out ----------------
// Same LDS-staged BK=64 double-buffered main loop as proj_gemm; direct fp32 epilogue stores.
__global__ __launch_bounds__(256) void out_gemm_kernel(const __bf16* __restrict__ Ob,
                                                       const __bf16* __restrict__ Wot,
                                                       const float* __restrict__ bo,
                                                       float* __restrict__ out) {
  int lane = threadIdx.x & 63, wv = threadIdx.x >> 6;
  int wr = wv >> 1, wc = wv & 1;
  int quad = lane >> 4, lc = lane & 15;
  int M0 = blockIdx.x * 128, N0 = blockIdx.y * 128;
  int m0 = M0 + wr * 64, n0 = N0 + wc * 64;

  __shared__ __align__(16) __bf16 smem[2 * 2 * 128 * 64];

  int srow = lane >> 3;
  int sg = ((lane & 7) ^ srow) * 8;

#pragma unroll
  for (int i = 0; i < 4; ++i) {
    int r0 = wv * 32 + i * 8;
    GLDS(Ob  + (M0 + r0 + srow) * D_ + sg, AB(0) + r0 * 64);
    GLDS(Wot + (N0 + r0 + srow) * D_ + sg, BB(0) + r0 * 64);
  }

  f32x4 acc[4][4];
#pragma unroll
  for (int mt = 0; mt < 4; mt++)
#pragma unroll
    for (int nt = 0; nt < 4; nt++) acc[mt][nt] = zero4();

  __syncthreads();

  for (int j = 0; j < 8; ++j) {
    int cb = j & 1;
    if (j < 7) {
      int k0 = (j + 1) * 64;
#pragma unroll
      for (int i = 0; i < 4; ++i) {
        int r0 = wv * 32 + i * 8;
        GLDS(Ob  + (M0 + r0 + srow) * D_ + k0 + sg, AB(cb ^ 1) + r0 * 64);
        GLDS(Wot + (N0 + r0 + srow) * D_ + k0 + sg, BB(cb ^ 1) + r0 * 64);
      }
    }
    const __bf16* Al = AB(cb);
    const __bf16* Bl = BB(cb);
#pragma unroll
    for (int kk = 0; kk < 2; ++kk) {
      int gp = ((kk * 4 + quad) ^ (lc & 7)) * 8;
      bf16x8 a[4], bb[4];
#pragma unroll
      for (int mt = 0; mt < 4; mt++)
        a[mt] = *(const bf16x8*)(Al + (wr * 64 + mt * 16 + lc) * 64 + gp);
#pragma unroll
      for (int nt = 0; nt < 4; nt++)
        bb[nt] = *(const bf16x8*)(Bl + (wc * 64 + nt * 16 + lc) * 64 + gp);
#pragma unroll
      for (int mt = 0; mt < 4; mt++)
#pragma unroll
        for (int nt = 0; nt < 4; nt++)
          acc[mt][nt] = mfma16(a[mt], bb[nt], acc[mt][nt]);
    }
    __syncthreads();
  }

#pragma unroll
  for (int nt = 0; nt < 4; nt++) {
    int col = n0 + nt * 16 + lc;
    float bval = bo[col];
#pragma unroll
    for (int mt = 0; mt < 4; mt++)
#pragma unroll
      for (int r = 0; r < 4; r++) {
        int row = m0 + mt * 16 + quad * 4 + r;
        out[row * D_ + col] = acc[mt][nt][r] + bval;
      }
  }
}

extern "C" void kernel_launch(void* const* d_in, const int* in_sizes, int n_in,
                              void* d_out, int out_size, void* d_ws, size_t ws_size,
                              hipStream_t stream) {
  const float* q  = (const float*)d_in[0];
  const float* k  = (const float*)d_in[1];
  const float* v  = (const float*)d_in[2];
  const float* Wq = (const float*)d_in[3];
  const float* bq = (const float*)d_in[4];
  const float* Wk = (const float*)d_in[5];
  const float* bk = (const float*)d_in[6];
  const float* Wv = (const float*)d_in[7];
  const float* bv = (const float*)d_in[8];
  const float* Wo = (const float*)d_in[9];
  const float* bo = (const float*)d_in[10];

  char* ws = (char*)d_ws;
  __bf16* Xq  = (__bf16*)(ws + 0);          // 8 MiB each
  __bf16* Xk  = (__bf16*)(ws + 8388608);
  __bf16* Xv  = (__bf16*)(ws + 16777216);
  __bf16* Wtq = (__bf16*)(ws + 25165824);   // 512 KiB each
  __bf16* Wtk = (__bf16*)(ws + 25690112);
  __bf16* Wtv = (__bf16*)(ws + 26214400);
  __bf16* Wot = (__bf16*)(ws + 26738688);
  __bf16* Qb  = (__bf16*)(ws + 27262976);   // 8 MiB each
  __bf16* Kb  = (__bf16*)(ws + 35651584);
  __bf16* Vtb = (__bf16*)(ws + 44040192);
  __bf16* Ob  = (__bf16*)(ws + 52428800);

  prep_all_kernel<<<12544, 256, 0, stream>>>(q, k, v, Wq, Wk, Wv, Wo,
                                             Xq, Xk, Xv, Wtq, Wtk, Wtv, Wot);
  proj_gemm_kernel<<<dim3(64, 4, 3), 256, 0, stream>>>(Xq, Xk, Xv, Wtq, Wtk, Wtv,
                                                       bq, bk, bv, Qb, Kb, Vtb);
  flash_kernel<<<dim3(512), 256, 0, stream>>>(Qb, Kb, Vtb, Ob);
  out_gemm_kernel<<<dim3(64, 4), 256, 0, stream>>>(Ob, Wot, bo, (float*)d_out);
}